// Round 10
// baseline (724.915 us; speedup 1.0000x reference)
//
#include <hip/hip_runtime.h>
#include <hip/hip_fp8.h>

#define P 196
#define NN 32
#define MARGIN 0.5f
#define NCH 12            // K-chunks of 64 fp8 elements
#define APIECES 896       // A: 224 rows * 4 pieces (16 B) per chunk
#define BPIECES 448       // B q-half: 112 rows * 4 pieces
#define TPB (APIECES + BPIECES)        // 1344 pieces per buffer
#define BUFB (TPB * 16)                // 21504 bytes per buffer
#define CHB (APIECES * 16)             // 14336 bytes per image-chunk
#define SC1 0x7F7F7F7F                 // E8M0 identity scales (1.0 x4)

typedef int intx4 __attribute__((ext_vector_type(4)));       // one 16-B LDS piece
typedef int intx8 __attribute__((ext_vector_type(8)));       // 32-B f8f6f4 operand
typedef float floatx4 __attribute__((ext_vector_type(4)));   // 16x16 MFMA C/D frag
#define CAT8(lo, hi) __builtin_shufflevector(lo, hi, 0, 1, 2, 3, 4, 5, 6, 7)

typedef __attribute__((address_space(1))) const unsigned char g_u8;
typedef __attribute__((address_space(3))) unsigned char l_u8;

// Workspace Y layout (fp8 e4m3, chunk-major, swizzled) — HW-verified R8/R9:
//   chunk c covers k = c*64..c*64+63. Piece(img,c,r,kg') = 16 B at
//   (img*12 + c)*14336 + (r*4 + kg')*16, kg' = kg ^ ((r>>1)&3).
//   K=128 operand = [chunk-2kp piece | chunk-2kp+1 piece]; k-order inside the
//   operand is irrelevant for a Gram matrix (both operands share the layout) —
//   numerics validated on HW in R9 (passed, absmax 0.0).

// ---------------------------------------------------------------------------
// Kernel 1 (unchanged from R8, HW-verified): 8 waves/block, one row per wave.
// fp32 normalize in registers, convert to OCP fp8 e4m3 via __hip_fp8_e4m3,
// buffer row in LDS, write chunk-major in 512-B segments. Pad rows (p>=196)
// keep the 0xAA ws poison (finite fp8, masked in consumers). Zero-inits out.
// ---------------------------------------------------------------------------
__global__ __launch_bounds__(512) void norm_kernel(const float* __restrict__ nrm,
                                                   const float* __restrict__ dft,
                                                   unsigned char* __restrict__ Y,
                                                   float* __restrict__ out) {
    if (blockIdx.x == 0 && threadIdx.x == 0) out[0] = 0.0f;
    __shared__ uint2 rowbuf[8][100];             // 96 groups of 8 fp8 per row

    int img  = blockIdx.x / 28;
    int rg   = blockIdx.x % 28;
    int wave = threadIdx.x >> 6;
    int lane = threadIdx.x & 63;
    int p = rg * 8 + wave;

    if (p < P) {
        const float* src = (img < NN) ? nrm + ((size_t)img * P + p) * 768
                                      : dft + ((size_t)(img - NN) * P + p) * 768;
        float4 a0 = *(const float4*)(src + lane * 8);
        float4 a1 = *(const float4*)(src + lane * 8 + 4);
        float4 b0 = {0,0,0,0}, b1 = {0,0,0,0};
        float ss = a0.x*a0.x + a0.y*a0.y + a0.z*a0.z + a0.w*a0.w
                 + a1.x*a1.x + a1.y*a1.y + a1.z*a1.z + a1.w*a1.w;
        if (lane < 32) {
            b0 = *(const float4*)(src + 512 + lane * 8);
            b1 = *(const float4*)(src + 512 + lane * 8 + 4);
            ss += b0.x*b0.x + b0.y*b0.y + b0.z*b0.z + b0.w*b0.w
                + b1.x*b1.x + b1.y*b1.y + b1.z*b1.z + b1.w*b1.w;
        }
        #pragma unroll
        for (int o = 32; o > 0; o >>= 1) ss += __shfl_xor(ss, o);
        float inv = 1.0f / (sqrtf(ss) + 1e-8f);

        auto q8 = [&](float f) -> unsigned {     // fp32 -> OCP e4m3 byte
            return (unsigned)__hip_fp8_e4m3(f).__x;
        };
        auto pack8 = [&](float4 x0, float4 x1) {
            uint2 g;
            g.x = q8(x0.x*inv) | (q8(x0.y*inv) << 8) |
                  (q8(x0.z*inv) << 16) | (q8(x0.w*inv) << 24);
            g.y = q8(x1.x*inv) | (q8(x1.y*inv) << 8) |
                  (q8(x1.z*inv) << 16) | (q8(x1.w*inv) << 24);
            return g;
        };
        rowbuf[wave][lane] = pack8(a0, a1);                     // groups 0..63
        if (lane < 32) rowbuf[wave][64 + lane] = pack8(b0, b1); // groups 64..95
    }
    __syncthreads();

    int idx = threadIdx.x;
    if (idx < 384) {
        int c = idx >> 5, r = (idx >> 2) & 7, kgp = idx & 3;
        int pr = rg * 8 + r;
        if (pr < P) {
            int kg = kgp ^ ((pr >> 1) & 3);
            uint2 lo = rowbuf[r][c * 8 + kg];        // s=0 half
            uint2 hi = rowbuf[r][c * 8 + 4 + kg];    // s=1 half
            uint4 o; o.x = lo.x; o.y = lo.y; o.z = hi.x; o.w = hi.y;
            *(uint4*)(Y + (size_t)(img * NCH + c) * CHB + (pr * 4 + kgp) * 16) = o;
        }
    }
}

// ---------------------------------------------------------------------------
// Kernel 2: two blocks per pair (q-halves), 256 threads = 4 waves.
// Waves 0-2: 4 p-subtiles; wave 3: 1 subtile -> 13 p-subtiles.
// MX path (mfma_scale_f32_16x16x128_f8f6f4, identity scales, 4661 TF).
// Liveness-engineered frag reads (the R9 spill fix):
//   - A ops built eagerly from lo+hi pieces (halves die; 32 regs live).
//   - B lo-halves (race-protection set: buffer `lo` is re-staged this iter)
//     read before the lgkm barrier; B hi-halves read lazily in the t-loop,
//     one operand live at a time (buffer `hi` is NOT staged this iter).
// Peak unified regs ~205 < 256 at 2 blocks/CU.
// ---------------------------------------------------------------------------
__global__ __launch_bounds__(256, 2) void pair_kernel(const unsigned char* __restrict__ Y,
                                                      float* __restrict__ out) {
    __shared__ uint4 tiles[3 * TPB];   // 64512 B (colmax aliased in epilogue)
    __shared__ float redp[4];

    int bx = blockIdx.x;
    int b  = bx >> 1;                // pair index
    int qh = bx & 1;                 // q-half
    int ia, ja; bool is_nn;
    if (b < 496) {
        is_nn = true;
        int i = 0, rem = b;
        while (rem >= 31 - i) { rem -= 31 - i; ++i; }   // triangular, i<j
        ia = i; ja = i + 1 + rem;
    } else {
        is_nn = false;
        int t = b - 496;
        ia = t & 31; ja = NN + (t >> 5);
    }

    int tid  = threadIdx.x;
    int lane = tid & 63;
    int wave = tid >> 6;             // 0..3
    int r16  = lane & 15;
    int quad = lane >> 4;            // 0..3 : k-group of 8
    int sw   = quad ^ ((r16 >> 1) & 3);   // XOR swizzle (verified conflict-free)

    const char* abp = (const char*)tiles + wave * 4096 + (r16 * 4 + sw) * 16;
    const char* bbp = (const char*)tiles + APIECES * 16 + (r16 * 4 + sw) * 16;

    floatx4 acc[4][7];
    #pragma unroll
    for (int ps = 0; ps < 4; ++ps)
        #pragma unroll
        for (int t = 0; t < 7; ++t)
            acc[ps][t] = (floatx4){0.f, 0.f, 0.f, 0.f};

    // 21 DMA instrs/chunk: i<14 = A pieces, i>=14 = B-half pieces.
    l_u8* lds0 = (l_u8*)&tiles[0];
    auto stage = [&](const unsigned char* ga, const unsigned char* gb, l_u8* ldsb) {
        #pragma unroll
        for (int u = 0; u < 5; ++u) {
            int i = wave + 4 * u;
            const unsigned char* g = (i < 14) ? ga + (i * 64 + lane) * 16
                                              : gb + ((i - 14) * 64 + lane) * 16;
            __builtin_amdgcn_global_load_lds((const g_u8*)g, ldsb + i * 1024, 16, 0, 0);
        }
        if (wave == 0)
            __builtin_amdgcn_global_load_lds((const g_u8*)(gb + (6 * 64 + lane) * 16),
                                             ldsb + 20 * 1024, 16, 0, 0);
    };

    const unsigned char* gA = Y + (size_t)ia * (NCH * CHB);
    const unsigned char* gB = Y + (size_t)ja * (NCH * CHB) + qh * (BPIECES * 16);
    stage(gA, gB, lds0);            gA += CHB; gB += CHB;
    stage(gA, gB, lds0 + BUFB);     gA += CHB; gB += CHB;

    auto ld4 = [](const char* p) { return *(const intx4*)p; };

    for (int kb = 0; kb < 6; kb += 3) {
        #pragma unroll
        for (int kk = 0; kk < 3; ++kk) {
            int kp = kb + kk;                    // K=128 step index (0..5)
            const int lo = (2 * kk) % 3;         // buffer of chunk 2kp (re-staged below)
            const int hi = (2 * kk + 1) % 3;     // buffer of chunk 2kp+1 (untouched this iter)

            __builtin_amdgcn_s_waitcnt(0xF70);   // vmcnt(0): both chunks landed
            __builtin_amdgcn_s_barrier();
            __builtin_amdgcn_sched_barrier(0);   // no ds_read above barrier

            // A operands: eager lo+hi -> intx8 (halves die immediately)
            intx8 aop[4];
            aop[0] = CAT8(ld4(abp + lo * BUFB), ld4(abp + hi * BUFB));
            if (wave < 3) {
                #pragma unroll
                for (int ps = 1; ps < 4; ++ps)
                    aop[ps] = CAT8(ld4(abp + lo * BUFB + ps * 1024),
                                   ld4(abp + hi * BUFB + ps * 1024));
            }
            // B lo-halves only (these reads must complete before buffer `lo`
            // is re-staged by any wave)
            intx4 blo[7];
            #pragma unroll
            for (int t = 0; t < 7; ++t)
                blo[t] = ld4(bbp + lo * BUFB + t * 1024);

            __builtin_amdgcn_s_waitcnt(0x07F);   // lgkmcnt(0): lo reads done
            __builtin_amdgcn_sched_barrier(0);
            __builtin_amdgcn_s_barrier();        // all waves' lo reads done
            __builtin_amdgcn_sched_barrier(0);   // no DMA above this barrier

            if (kp < 5) {                        // stage chunks 2kp+2, 2kp+3
                stage(gA, gB, lds0 + ((2 * kp + 2) % 3) * BUFB);
                gA += CHB; gB += CHB;
                stage(gA, gB, lds0 + ((2 * kp + 3) % 3) * BUFB);  // == buf `lo`
                gA += CHB; gB += CHB;
            }

            // t-loop: B hi-half read lazily (buffer `hi` is safe), one B
            // operand live at a time, consumed by its 4 MFMAs immediately
            #pragma unroll
            for (int t = 0; t < 7; ++t) {
                intx8 bop = CAT8(blo[t], ld4(bbp + hi * BUFB + t * 1024));
                acc[0][t] = __builtin_amdgcn_mfma_scale_f32_16x16x128_f8f6f4(
                    aop[0], bop, acc[0][t], 0, 0, 0, SC1, 0, SC1);
                if (wave < 3) {
                    #pragma unroll
                    for (int ps = 1; ps < 4; ++ps)
                        acc[ps][t] = __builtin_amdgcn_mfma_scale_f32_16x16x128_f8f6f4(
                            aop[ps], bop, acc[ps][t], 0, 0, 0, SC1, 0, SC1);
                }
            }
        }
    }

    __syncthreads();                 // all tile reads done; alias as colmax
    float* colmax = (float*)tiles;   // [4][112]

    // C/D: col q = lane&15, row p = quad*4 + r (shape-determined, verified)
    #pragma unroll
    for (int t = 0; t < 7; ++t) {
        float m = -3.0e38f;
        #pragma unroll
        for (int ps = 0; ps < 4; ++ps) {
            int pbase = wave * 64 + ps * 16 + quad * 4;
            #pragma unroll
            for (int r = 0; r < 4; ++r)
                if (pbase + r < P) m = fmaxf(m, acc[ps][t][r]);
        }
        m = fmaxf(m, __shfl_xor(m, 16));
        m = fmaxf(m, __shfl_xor(m, 32));
        if (quad == 0) colmax[wave * 112 + t * 16 + r16] = m;
    }
    __syncthreads();

    float contrib = 0.f;
    if (tid < 112 && qh * 112 + tid < P) {       // q >= 196 are pad cols
        float cm = fmaxf(fmaxf(colmax[tid], colmax[112 + tid]),
                         fmaxf(colmax[224 + tid], colmax[336 + tid]));
        contrib = is_nn ? (1.0f - cm) * (1.0f / (496.0f * 196.0f))
                        : fmaxf(cm - MARGIN, 0.0f) * (1.0f / (1024.0f * 196.0f));
    }
    #pragma unroll
    for (int o = 32; o > 0; o >>= 1) contrib += __shfl_down(contrib, o);
    if (lane == 0) redp[wave] = contrib;
    __syncthreads();
    if (tid == 0)
        atomicAdd(out, redp[0] + redp[1] + redp[2] + redp[3]);
}

// ---------------------------------------------------------------------------
extern "C" void kernel_launch(void* const* d_in, const int* in_sizes, int n_in,
                              void* d_out, int out_size, void* d_ws, size_t ws_size,
                              hipStream_t stream) {
    const float* nrm = (const float*)d_in[0];   // [32,196,768] fp32
    const float* dft = (const float*)d_in[1];   // [32,196,768] fp32
    float* out = (float*)d_out;                 // scalar fp32
    unsigned char* Y = (unsigned char*)d_ws;    // fp8 e4m3, 10.5 MB

    norm_kernel<<<64 * 28, 512, 0, stream>>>(nrm, dft, Y, out);
    pair_kernel<<<2 * (496 + 1024), 256, 0, stream>>>(Y, out);
}

// Round 11
// 204.733 us; speedup vs baseline: 3.5408x; 3.5408x over previous
//
#include <hip/hip_runtime.h>
#include <hip/hip_fp8.h>

#define P 196
#define NN 32
#define MARGIN 0.5f
#define NCH 12            // K-chunks of 64 fp8 elements
#define APIECES 896       // A: 224 rows * 4 pieces (16 B) per chunk
#define BPIECES 448       // B q-half: 112 rows * 4 pieces
#define TPB (APIECES + BPIECES)        // 1344 pieces per buffer
#define BUFB (TPB * 16)                // 21504 bytes per buffer
#define CHB (APIECES * 16)             // 14336 bytes per image-chunk
#define SC1 0x7F7F7F7F                 // E8M0 identity scales (1.0 x4)

typedef int intx4 __attribute__((ext_vector_type(4)));       // one 16-B LDS piece
typedef int intx8 __attribute__((ext_vector_type(8)));       // 32-B f8f6f4 operand
typedef float floatx4 __attribute__((ext_vector_type(4)));   // 16x16 MFMA C/D frag
#define CAT8(lo, hi) __builtin_shufflevector(lo, hi, 0, 1, 2, 3, 4, 5, 6, 7)

typedef __attribute__((address_space(1))) const unsigned char g_u8;
typedef __attribute__((address_space(3))) unsigned char l_u8;

// Workspace Y layout (fp8 e4m3, chunk-major, swizzled) — HW-verified R8/R9:
//   chunk c covers k = c*64..c*64+63. Piece(img,c,r,kg') = 16 B at
//   (img*12 + c)*14336 + (r*4 + kg')*16, kg' = kg ^ ((r>>1)&3).
//   K=128 operand = [chunk-2kp piece | chunk-2kp+1 piece]; k-order inside the
//   operand is irrelevant for a Gram matrix (A and B share the lane->k map) —
//   numerics validated on HW in R9 (passed, absmax 0.0).

// ---------------------------------------------------------------------------
// Kernel 1 (unchanged from R8, HW-verified): 8 waves/block, one row per wave.
// fp32 normalize in registers, convert to OCP fp8 e4m3 via __hip_fp8_e4m3,
// buffer row in LDS, write chunk-major in 512-B segments. Pad rows (p>=196)
// keep the 0xAA ws poison (finite fp8, masked in consumers). Zero-inits out.
// ---------------------------------------------------------------------------
__global__ __launch_bounds__(512) void norm_kernel(const float* __restrict__ nrm,
                                                   const float* __restrict__ dft,
                                                   unsigned char* __restrict__ Y,
                                                   float* __restrict__ out) {
    if (blockIdx.x == 0 && threadIdx.x == 0) out[0] = 0.0f;
    __shared__ uint2 rowbuf[8][100];             // 96 groups of 8 fp8 per row

    int img  = blockIdx.x / 28;
    int rg   = blockIdx.x % 28;
    int wave = threadIdx.x >> 6;
    int lane = threadIdx.x & 63;
    int p = rg * 8 + wave;

    if (p < P) {
        const float* src = (img < NN) ? nrm + ((size_t)img * P + p) * 768
                                      : dft + ((size_t)(img - NN) * P + p) * 768;
        float4 a0 = *(const float4*)(src + lane * 8);
        float4 a1 = *(const float4*)(src + lane * 8 + 4);
        float4 b0 = {0,0,0,0}, b1 = {0,0,0,0};
        float ss = a0.x*a0.x + a0.y*a0.y + a0.z*a0.z + a0.w*a0.w
                 + a1.x*a1.x + a1.y*a1.y + a1.z*a1.z + a1.w*a1.w;
        if (lane < 32) {
            b0 = *(const float4*)(src + 512 + lane * 8);
            b1 = *(const float4*)(src + 512 + lane * 8 + 4);
            ss += b0.x*b0.x + b0.y*b0.y + b0.z*b0.z + b0.w*b0.w
                + b1.x*b1.x + b1.y*b1.y + b1.z*b1.z + b1.w*b1.w;
        }
        #pragma unroll
        for (int o = 32; o > 0; o >>= 1) ss += __shfl_xor(ss, o);
        float inv = 1.0f / (sqrtf(ss) + 1e-8f);

        auto q8 = [&](float f) -> unsigned {     // fp32 -> OCP e4m3 byte
            return (unsigned)__hip_fp8_e4m3(f).__x;
        };
        auto pack8 = [&](float4 x0, float4 x1) {
            uint2 g;
            g.x = q8(x0.x*inv) | (q8(x0.y*inv) << 8) |
                  (q8(x0.z*inv) << 16) | (q8(x0.w*inv) << 24);
            g.y = q8(x1.x*inv) | (q8(x1.y*inv) << 8) |
                  (q8(x1.z*inv) << 16) | (q8(x1.w*inv) << 24);
            return g;
        };
        rowbuf[wave][lane] = pack8(a0, a1);                     // groups 0..63
        if (lane < 32) rowbuf[wave][64 + lane] = pack8(b0, b1); // groups 64..95
    }
    __syncthreads();

    int idx = threadIdx.x;
    if (idx < 384) {
        int c = idx >> 5, r = (idx >> 2) & 7, kgp = idx & 3;
        int pr = rg * 8 + r;
        if (pr < P) {
            int kg = kgp ^ ((pr >> 1) & 3);
            uint2 lo = rowbuf[r][c * 8 + kg];        // s=0 half
            uint2 hi = rowbuf[r][c * 8 + 4 + kg];    // s=1 half
            uint4 o; o.x = lo.x; o.y = lo.y; o.z = hi.x; o.w = hi.y;
            *(uint4*)(Y + (size_t)(img * NCH + c) * CHB + (pr * 4 + kgp) * 16) = o;
        }
    }
}

// ---------------------------------------------------------------------------
// Kernel 2: two blocks per pair (q-halves), 256 threads = 4 waves.
// Waves 0-2: 4 p-subtiles; wave 3: 1 subtile -> 13 p-subtiles.
// MX path (mfma_scale_f32_16x16x128_f8f6f4, identity scales, 4661 TF).
// R11 change vs R10: __launch_bounds__(256) WITHOUT the min-waves clamp.
// Theory: (256,2) imposed a 256-unified-reg budget that the compiler split
// 128 arch / 128 acc; the scaled MFMA needs C/D in arch VGPRs -> acc (112)
// couldn't fit the 128-arch half -> per-iter accumulator spill (R9/R10's
// 1.9 GB scratch WRITE_SIZE, VGPR_Count pinned at 128). Unbounded, the
// allocator can take ~220 arch regs; total stays <=256 so 2 waves/SIMD
// occupancy is preserved (LDS 63 KB already caps at 2 blocks/CU).
// ---------------------------------------------------------------------------
__global__ __launch_bounds__(256) void pair_kernel(const unsigned char* __restrict__ Y,
                                                   float* __restrict__ out) {
    __shared__ uint4 tiles[3 * TPB];   // 64512 B (colmax aliased in epilogue)
    __shared__ float redp[4];

    int bx = blockIdx.x;
    int b  = bx >> 1;                // pair index
    int qh = bx & 1;                 // q-half
    int ia, ja; bool is_nn;
    if (b < 496) {
        is_nn = true;
        int i = 0, rem = b;
        while (rem >= 31 - i) { rem -= 31 - i; ++i; }   // triangular, i<j
        ia = i; ja = i + 1 + rem;
    } else {
        is_nn = false;
        int t = b - 496;
        ia = t & 31; ja = NN + (t >> 5);
    }

    int tid  = threadIdx.x;
    int lane = tid & 63;
    int wave = tid >> 6;             // 0..3
    int r16  = lane & 15;
    int quad = lane >> 4;            // 0..3 : k-group of 8
    int sw   = quad ^ ((r16 >> 1) & 3);   // XOR swizzle (verified conflict-free)

    const char* abp = (const char*)tiles + wave * 4096 + (r16 * 4 + sw) * 16;
    const char* bbp = (const char*)tiles + APIECES * 16 + (r16 * 4 + sw) * 16;

    floatx4 acc[4][7];
    #pragma unroll
    for (int ps = 0; ps < 4; ++ps)
        #pragma unroll
        for (int t = 0; t < 7; ++t)
            acc[ps][t] = (floatx4){0.f, 0.f, 0.f, 0.f};

    // 21 DMA instrs/chunk: i<14 = A pieces, i>=14 = B-half pieces.
    l_u8* lds0 = (l_u8*)&tiles[0];
    auto stage = [&](const unsigned char* ga, const unsigned char* gb, l_u8* ldsb) {
        #pragma unroll
        for (int u = 0; u < 5; ++u) {
            int i = wave + 4 * u;
            const unsigned char* g = (i < 14) ? ga + (i * 64 + lane) * 16
                                              : gb + ((i - 14) * 64 + lane) * 16;
            __builtin_amdgcn_global_load_lds((const g_u8*)g, ldsb + i * 1024, 16, 0, 0);
        }
        if (wave == 0)
            __builtin_amdgcn_global_load_lds((const g_u8*)(gb + (6 * 64 + lane) * 16),
                                             ldsb + 20 * 1024, 16, 0, 0);
    };

    const unsigned char* gA = Y + (size_t)ia * (NCH * CHB);
    const unsigned char* gB = Y + (size_t)ja * (NCH * CHB) + qh * (BPIECES * 16);
    stage(gA, gB, lds0);            gA += CHB; gB += CHB;
    stage(gA, gB, lds0 + BUFB);     gA += CHB; gB += CHB;

    auto ld4 = [](const char* p) { return *(const intx4*)p; };

    for (int kb = 0; kb < 6; kb += 3) {
        #pragma unroll
        for (int kk = 0; kk < 3; ++kk) {
            int kp = kb + kk;                    // K=128 step index (0..5)
            const int lo = (2 * kk) % 3;         // buffer of chunk 2kp (re-staged below)
            const int hi = (2 * kk + 1) % 3;     // buffer of chunk 2kp+1 (untouched this iter)

            __builtin_amdgcn_s_waitcnt(0xF70);   // vmcnt(0): both chunks landed
            __builtin_amdgcn_s_barrier();
            __builtin_amdgcn_sched_barrier(0);   // no ds_read above barrier

            // A operands: eager lo+hi -> intx8 (halves die immediately)
            intx8 aop[4];
            aop[0] = CAT8(ld4(abp + lo * BUFB), ld4(abp + hi * BUFB));
            if (wave < 3) {
                #pragma unroll
                for (int ps = 1; ps < 4; ++ps)
                    aop[ps] = CAT8(ld4(abp + lo * BUFB + ps * 1024),
                                   ld4(abp + hi * BUFB + ps * 1024));
            }
            // B lo-halves only (these reads must complete before buffer `lo`
            // is re-staged by any wave)
            intx4 blo[7];
            #pragma unroll
            for (int t = 0; t < 7; ++t)
                blo[t] = ld4(bbp + lo * BUFB + t * 1024);

            __builtin_amdgcn_s_waitcnt(0x07F);   // lgkmcnt(0): lo reads done
            __builtin_amdgcn_sched_barrier(0);
            __builtin_amdgcn_s_barrier();        // all waves' lo reads done
            __builtin_amdgcn_sched_barrier(0);   // no DMA above this barrier

            if (kp < 5) {                        // stage chunks 2kp+2, 2kp+3
                stage(gA, gB, lds0 + ((2 * kp + 2) % 3) * BUFB);
                gA += CHB; gB += CHB;
                stage(gA, gB, lds0 + ((2 * kp + 3) % 3) * BUFB);  // == buf `lo`
                gA += CHB; gB += CHB;
            }

            // t-loop: B hi-half read lazily (buffer `hi` is safe), one B
            // operand live at a time, consumed by its 4 MFMAs immediately
            #pragma unroll
            for (int t = 0; t < 7; ++t) {
                intx8 bop = CAT8(blo[t], ld4(bbp + hi * BUFB + t * 1024));
                acc[0][t] = __builtin_amdgcn_mfma_scale_f32_16x16x128_f8f6f4(
                    aop[0], bop, acc[0][t], 0, 0, 0, SC1, 0, SC1);
                if (wave < 3) {
                    #pragma unroll
                    for (int ps = 1; ps < 4; ++ps)
                        acc[ps][t] = __builtin_amdgcn_mfma_scale_f32_16x16x128_f8f6f4(
                            aop[ps], bop, acc[ps][t], 0, 0, 0, SC1, 0, SC1);
                }
            }
        }
    }

    __syncthreads();                 // all tile reads done; alias as colmax
    float* colmax = (float*)tiles;   // [4][112]

    // C/D: col q = lane&15, row p = quad*4 + r (shape-determined, verified)
    #pragma unroll
    for (int t = 0; t < 7; ++t) {
        float m = -3.0e38f;
        #pragma unroll
        for (int ps = 0; ps < 4; ++ps) {
            int pbase = wave * 64 + ps * 16 + quad * 4;
            #pragma unroll
            for (int r = 0; r < 4; ++r)
                if (pbase + r < P) m = fmaxf(m, acc[ps][t][r]);
        }
        m = fmaxf(m, __shfl_xor(m, 16));
        m = fmaxf(m, __shfl_xor(m, 32));
        if (quad == 0) colmax[wave * 112 + t * 16 + r16] = m;
    }
    __syncthreads();

    float contrib = 0.f;
    if (tid < 112 && qh * 112 + tid < P) {       // q >= 196 are pad cols
        float cm = fmaxf(fmaxf(colmax[tid], colmax[112 + tid]),
                         fmaxf(colmax[224 + tid], colmax[336 + tid]));
        contrib = is_nn ? (1.0f - cm) * (1.0f / (496.0f * 196.0f))
                        : fmaxf(cm - MARGIN, 0.0f) * (1.0f / (1024.0f * 196.0f));
    }
    #pragma unroll
    for (int o = 32; o > 0; o >>= 1) contrib += __shfl_down(contrib, o);
    if (lane == 0) redp[wave] = contrib;
    __syncthreads();
    if (tid == 0)
        atomicAdd(out, redp[0] + redp[1] + redp[2] + redp[3]);
}

// ---------------------------------------------------------------------------
extern "C" void kernel_launch(void* const* d_in, const int* in_sizes, int n_in,
                              void* d_out, int out_size, void* d_ws, size_t ws_size,
                              hipStream_t stream) {
    const float* nrm = (const float*)d_in[0];   // [32,196,768] fp32
    const float* dft = (const float*)d_in[1];   // [32,196,768] fp32
    float* out = (float*)d_out;                 // scalar fp32
    unsigned char* Y = (unsigned char*)d_ws;    // fp8 e4m3, 10.5 MB

    norm_kernel<<<64 * 28, 512, 0, stream>>>(nrm, dft, Y, out);
    pair_kernel<<<2 * (496 + 1024), 256, 0, stream>>>(Y, out);
}

// Round 12
// 167.287 us; speedup vs baseline: 4.3334x; 1.2238x over previous
//
#include <hip/hip_runtime.h>
#include <hip/hip_fp8.h>

#define P 196
#define NN 32
#define MARGIN 0.5f
#define NCH 12            // K-chunks of 64 fp8 elements
#define APIECES 896       // A: 224 rows * 4 pieces (16 B) per chunk
#define BPIECES 448       // B q-half: 112 rows * 4 pieces
#define TPB (APIECES + BPIECES)        // 1344 pieces per buffer
#define BUFB (TPB * 16)                // 21504 bytes per buffer
#define CHB (APIECES * 16)             // 14336 bytes per image-chunk

typedef long longx2 __attribute__((ext_vector_type(2)));     // 16 B = 2 fp8 half-frags
typedef float floatx4 __attribute__((ext_vector_type(4)));   // 16x16 MFMA C/D frag

typedef __attribute__((address_space(1))) const unsigned char g_u8;
typedef __attribute__((address_space(3))) unsigned char l_u8;

// Workspace Y layout (fp8 e4m3, chunk-major, swizzled) — HW-verified R8:
//   chunk c covers k = c*64..c*64+63. Piece(img,c,r,kg') = 16 B at
//   (img*12 + c)*14336 + (r*4 + kg')*16, kg' = kg ^ ((r>>1)&3).
//   Piece bytes 0-7 = k_local [kg*8,+8) (s=0); bytes 8-15 = [32+kg*8,+8) (s=1)
//   -> one ds_read_b128 feeds TWO 16x16x32 fp8 MFMAs.

// ---------------------------------------------------------------------------
// Kernel 1 (unchanged from R8, HW-verified): 8 waves/block, one row per wave.
// fp32 normalize in registers, convert to OCP fp8 e4m3 via __hip_fp8_e4m3,
// buffer row in LDS, write chunk-major in 512-B segments. Pad rows (p>=196)
// keep the 0xAA ws poison (finite fp8, masked in consumers). Zero-inits out.
// ---------------------------------------------------------------------------
__global__ __launch_bounds__(512) void norm_kernel(const float* __restrict__ nrm,
                                                   const float* __restrict__ dft,
                                                   unsigned char* __restrict__ Y,
                                                   float* __restrict__ out) {
    if (blockIdx.x == 0 && threadIdx.x == 0) out[0] = 0.0f;
    __shared__ uint2 rowbuf[8][100];             // 96 groups of 8 fp8 per row

    int img  = blockIdx.x / 28;
    int rg   = blockIdx.x % 28;
    int wave = threadIdx.x >> 6;
    int lane = threadIdx.x & 63;
    int p = rg * 8 + wave;

    if (p < P) {
        const float* src = (img < NN) ? nrm + ((size_t)img * P + p) * 768
                                      : dft + ((size_t)(img - NN) * P + p) * 768;
        float4 a0 = *(const float4*)(src + lane * 8);
        float4 a1 = *(const float4*)(src + lane * 8 + 4);
        float4 b0 = {0,0,0,0}, b1 = {0,0,0,0};
        float ss = a0.x*a0.x + a0.y*a0.y + a0.z*a0.z + a0.w*a0.w
                 + a1.x*a1.x + a1.y*a1.y + a1.z*a1.z + a1.w*a1.w;
        if (lane < 32) {
            b0 = *(const float4*)(src + 512 + lane * 8);
            b1 = *(const float4*)(src + 512 + lane * 8 + 4);
            ss += b0.x*b0.x + b0.y*b0.y + b0.z*b0.z + b0.w*b0.w
                + b1.x*b1.x + b1.y*b1.y + b1.z*b1.z + b1.w*b1.w;
        }
        #pragma unroll
        for (int o = 32; o > 0; o >>= 1) ss += __shfl_xor(ss, o);
        float inv = 1.0f / (sqrtf(ss) + 1e-8f);

        auto q8 = [&](float f) -> unsigned {     // fp32 -> OCP e4m3 byte
            return (unsigned)__hip_fp8_e4m3(f).__x;
        };
        auto pack8 = [&](float4 x0, float4 x1) {
            uint2 g;
            g.x = q8(x0.x*inv) | (q8(x0.y*inv) << 8) |
                  (q8(x0.z*inv) << 16) | (q8(x0.w*inv) << 24);
            g.y = q8(x1.x*inv) | (q8(x1.y*inv) << 8) |
                  (q8(x1.z*inv) << 16) | (q8(x1.w*inv) << 24);
            return g;
        };
        rowbuf[wave][lane] = pack8(a0, a1);                     // groups 0..63
        if (lane < 32) rowbuf[wave][64 + lane] = pack8(b0, b1); // groups 64..95
    }
    __syncthreads();

    int idx = threadIdx.x;
    if (idx < 384) {
        int c = idx >> 5, r = (idx >> 2) & 7, kgp = idx & 3;
        int pr = rg * 8 + r;
        if (pr < P) {
            int kg = kgp ^ ((pr >> 1) & 3);
            uint2 lo = rowbuf[r][c * 8 + kg];        // s=0 half
            uint2 hi = rowbuf[r][c * 8 + 4 + kg];    // s=1 half
            uint4 o; o.x = lo.x; o.y = lo.y; o.z = hi.x; o.w = hi.y;
            *(uint4*)(Y + (size_t)(img * NCH + c) * CHB + (pr * 4 + kgp) * 16) = o;
        }
    }
}

// ---------------------------------------------------------------------------
// Kernel 2: R8 (proven 100.9 us, non-scaled fp8 MFMA) + SIMD load balancing.
// 13 p-subtiles of 16 rows split {4,3,3,3}; the heavy wave is wave 0 for
// even blocks (qh=0) and wave 3 for odd blocks (qh=1). Co-resident blocks
// are consecutive bx -> opposite parity -> per-SIMD subtile-streams become
// 7/7/6/6 instead of 8/8/8/2 (critical path -12.5%). Swizzle is invariant
// (subtile base rows are multiples of 16). Everything else identical to R8.
// ---------------------------------------------------------------------------
__global__ __launch_bounds__(256, 2) void pair_kernel(const unsigned char* __restrict__ Y,
                                                      float* __restrict__ out) {
    __shared__ uint4 tiles[3 * TPB];   // 64512 B (colmax aliased in epilogue)
    __shared__ float redp[4];

    int bx = blockIdx.x;
    int b  = bx >> 1;                // pair index
    int qh = bx & 1;                 // q-half
    int ia, ja; bool is_nn;
    if (b < 496) {
        is_nn = true;
        int i = 0, rem = b;
        while (rem >= 31 - i) { rem -= 31 - i; ++i; }   // triangular, i<j
        ia = i; ja = i + 1 + rem;
    } else {
        is_nn = false;
        int t = b - 496;
        ia = t & 31; ja = NN + (t >> 5);
    }

    int tid  = threadIdx.x;
    int lane = tid & 63;
    int wave = tid >> 6;             // 0..3
    int r16  = lane & 15;
    int quad = lane >> 4;            // 0..3 : k-group of 8
    int sw   = quad ^ ((r16 >> 1) & 3);   // XOR swizzle (verified conflict-free)

    // balanced subtile assignment: heavy wave h has 4 subtiles, others 3
    int h     = qh ? 3 : 0;
    int start = wave * 3 + ((h == 0 && wave > 0) ? 1 : 0);  // global subtile base
    bool heavy = (wave == h);

    const char* abp = (const char*)tiles + (r16 * 4 + sw) * 16;
    const char* bbp = (const char*)tiles + APIECES * 16 + (r16 * 4 + sw) * 16;

    floatx4 acc[4][7];
    #pragma unroll
    for (int ps = 0; ps < 4; ++ps)
        #pragma unroll
        for (int t = 0; t < 7; ++t)
            acc[ps][t] = (floatx4){0.f, 0.f, 0.f, 0.f};

    // 21 DMA instrs/chunk: i<14 = A pieces, i>=14 = B-half pieces.
    l_u8* lds0 = (l_u8*)&tiles[0];
    auto stage = [&](const unsigned char* ga, const unsigned char* gb, l_u8* ldsb) {
        #pragma unroll
        for (int u = 0; u < 5; ++u) {
            int i = wave + 4 * u;
            const unsigned char* g = (i < 14) ? ga + (i * 64 + lane) * 16
                                              : gb + ((i - 14) * 64 + lane) * 16;
            __builtin_amdgcn_global_load_lds((const g_u8*)g, ldsb + i * 1024, 16, 0, 0);
        }
        if (wave == 0)
            __builtin_amdgcn_global_load_lds((const g_u8*)(gb + (6 * 64 + lane) * 16),
                                             ldsb + 20 * 1024, 16, 0, 0);
    };

    const unsigned char* gA = Y + (size_t)ia * (NCH * CHB);
    const unsigned char* gB = Y + (size_t)ja * (NCH * CHB) + qh * (BPIECES * 16);
    stage(gA, gB, lds0);            gA += CHB; gB += CHB;
    stage(gA, gB, lds0 + BUFB);     gA += CHB; gB += CHB;

    for (int cb = 0; cb < NCH; cb += 3) {
        #pragma unroll
        for (int cc = 0; cc < 3; ++cc) {
            int c = cb + cc;
            // wait for chunk c's DMAs only (leave chunk c+1's in flight)
            if (c == NCH - 1)    __builtin_amdgcn_s_waitcnt(0xF70);  // vmcnt(0)
            else if (wave == 0)  __builtin_amdgcn_s_waitcnt(0xF76);  // vmcnt(6)
            else                 __builtin_amdgcn_s_waitcnt(0xF75);  // vmcnt(5)
            __builtin_amdgcn_s_barrier();
            __builtin_amdgcn_sched_barrier(0);   // pin: no ds_read above barrier

            longx2 afr[4], bfr[7];
            #pragma unroll
            for (int ps = 0; ps < 3; ++ps)
                afr[ps] = *(const longx2*)(abp + cc * BUFB + (start + ps) * 1024);
            if (heavy)
                afr[3] = *(const longx2*)(abp + cc * BUFB + (start + 3) * 1024);
            #pragma unroll
            for (int t = 0; t < 7; ++t)
                bfr[t] = *(const longx2*)(bbp + cc * BUFB + t * 1024);

            if (c + 2 < NCH) {
                stage(gA, gB, lds0 + ((cc + 2) % 3) * BUFB);
                gA += CHB; gB += CHB;
            }

            #pragma unroll
            for (int s = 0; s < 2; ++s) {        // two K=32 steps per chunk
                #pragma unroll
                for (int ps = 0; ps < 3; ++ps)
                    #pragma unroll
                    for (int t = 0; t < 7; ++t)
                        acc[ps][t] = __builtin_amdgcn_mfma_f32_16x16x32_fp8_fp8(
                            afr[ps][s], bfr[t][s], acc[ps][t], 0, 0, 0);
                if (heavy) {
                    #pragma unroll
                    for (int t = 0; t < 7; ++t)
                        acc[3][t] = __builtin_amdgcn_mfma_f32_16x16x32_fp8_fp8(
                            afr[3][s], bfr[t][s], acc[3][t], 0, 0, 0);
                }
            }
        }
    }

    __syncthreads();                 // all tile reads done; alias as colmax
    float* colmax = (float*)tiles;   // [4][112]

    // C/D: col q = lane&15, row p = quad*4 + r (within subtile)
    #pragma unroll
    for (int t = 0; t < 7; ++t) {
        float m = -3.0e38f;
        #pragma unroll
        for (int ps = 0; ps < 4; ++ps) {
            if (ps == 3 && !heavy) break;
            int pbase = (start + ps) * 16 + quad * 4;
            #pragma unroll
            for (int r = 0; r < 4; ++r)
                if (pbase + r < P) m = fmaxf(m, acc[ps][t][r]);
        }
        m = fmaxf(m, __shfl_xor(m, 16));
        m = fmaxf(m, __shfl_xor(m, 32));
        if (quad == 0) colmax[wave * 112 + t * 16 + r16] = m;
    }
    __syncthreads();

    float contrib = 0.f;
    if (tid < 112 && qh * 112 + tid < P) {       // q >= 196 are pad cols
        float cm = fmaxf(fmaxf(colmax[tid], colmax[112 + tid]),
                         fmaxf(colmax[224 + tid], colmax[336 + tid]));
        contrib = is_nn ? (1.0f - cm) * (1.0f / (496.0f * 196.0f))
                        : fmaxf(cm - MARGIN, 0.0f) * (1.0f / (1024.0f * 196.0f));
    }
    #pragma unroll
    for (int o = 32; o > 0; o >>= 1) contrib += __shfl_down(contrib, o);
    if (lane == 0) redp[wave] = contrib;
    __syncthreads();
    if (tid == 0)
        atomicAdd(out, redp[0] + redp[1] + redp[2] + redp[3]);
}

// ---------------------------------------------------------------------------
extern "C" void kernel_launch(void* const* d_in, const int* in_sizes, int n_in,
                              void* d_out, int out_size, void* d_ws, size_t ws_size,
                              hipStream_t stream) {
    const float* nrm = (const float*)d_in[0];   // [32,196,768] fp32
    const float* dft = (const float*)d_in[1];   // [32,196,768] fp32
    float* out = (float*)d_out;                 // scalar fp32
    unsigned char* Y = (unsigned char*)d_ws;    // fp8 e4m3, 10.5 MB

    norm_kernel<<<64 * 28, 512, 0, stream>>>(nrm, dft, Y, out);
    pair_kernel<<<2 * (496 + 1024), 256, 0, stream>>>(Y, out);
}